// Round 4
// baseline (80.699 us; speedup 1.0000x reference)
//
#include <hip/hip_runtime.h>
#include <float.h>

// PoseLoss: pred = model @ R^T + t; NN(pred, targets) for symmetric ids
// {0,7,12,20}; loss = mean_b mean_n ||pred - tgt||. B=128, N=1000, fp32.
//
// R4 changes vs R3:
//  - sym staging: coalesced float4 loads (targets block is 16B-aligned) into
//    raw xyz LDS layout; removes 6 scattered stride-12 scalar loads/thread.
//  - scan computes |p-t|^2 directly -> winner's distance is the answer
//    (acc = sqrt(bestd)), no post-argmin LDS gather needed.
//  - reduce kernel reads partials as float4.

#define BATCH 128
#define NPTS  1000
#define SPLIT 16
#define PTS_PER_BLK 64                 // points per block
#define LANES_PER_PT 8
#define JCHUNK (NPTS / LANES_PER_PT)   // 125
#define THREADS 512
#define NBLK (BATCH * SPLIT)           // 2048

__global__ __launch_bounds__(THREADS) void pose_loss_kernel(
    const float* __restrict__ pred_r,        // [B,3,3]
    const float* __restrict__ pred_t,        // [B,1,3]
    const float* __restrict__ targets,       // [B,N,3]
    const float* __restrict__ model_points,  // [B,N,3]
    const int*   __restrict__ idxs,          // [B]
    float* __restrict__ partial)             // [NBLK]
{
    const int b   = blockIdx.x / SPLIT;
    const int s   = blockIdx.x % SPLIT;
    const int tid = threadIdx.x;

    const int id = idxs[b];
    const bool sym = (id == 0) | (id == 7) | (id == 12) | (id == 20);

    // batch-uniform R, t -> scalar loads
    const float* Rb = pred_r + b * 9;
    const float* Tb = pred_t + b * 3;
    const float R00 = Rb[0], R01 = Rb[1], R02 = Rb[2];
    const float R10 = Rb[3], R11 = Rb[4], R12 = Rb[5];
    const float R20 = Rb[6], R21 = Rb[7], R22 = Rb[8];
    const float T0 = Tb[0], T1 = Tb[1], T2 = Tb[2];

    __shared__ float tsh[3 * NPTS];   // 12 KB, raw xyz layout
    if (sym) {
        // 3000 floats = 750 float4; base offset b*12000 B is 16B-aligned
        const float4* tb4 =
            reinterpret_cast<const float4*>(targets + (size_t)b * 3 * NPTS);
        float4* tsh4 = reinterpret_cast<float4*>(tsh);
        #pragma unroll
        for (int k = tid; k < (3 * NPTS) / 4; k += THREADS)
            tsh4[k] = tb4[k];                  // coalesced 16B/lane -> b128 LDS
        __syncthreads();
    }

    const int iloc = tid >> 3;        // 0..63
    const int sub  = tid & 7;         // lane within octet
    const int i    = s * PTS_PER_BLK + iloc;

    float acc = 0.0f;
    if (i < NPTS) {
        const float* mp = model_points + ((size_t)b * NPTS + i) * 3;
        const float m0 = mp[0], m1 = mp[1], m2 = mp[2];
        const float px = fmaf(m0, R00, fmaf(m1, R01, fmaf(m2, R02, T0)));
        const float py = fmaf(m0, R10, fmaf(m1, R11, fmaf(m2, R12, T1)));
        const float pz = fmaf(m0, R20, fmaf(m1, R21, fmaf(m2, R22, T2)));

        if (sym) {
            float bestd = FLT_MAX;
            int   bestj = sub * JCHUNK;
            const int j0 = sub * JCHUNK;
            // per-instr banks: dword 375*sub + (3it+c); 375 = 23 mod 32,
            // coprime with 32 -> 8 distinct banks, broadcast across octets.
            #pragma unroll 5
            for (int j = j0; j < j0 + JCHUNK; ++j) {
                const float dx = px - tsh[3 * j + 0];
                const float dy = py - tsh[3 * j + 1];
                const float dz = pz - tsh[3 * j + 2];
                const float d2 = fmaf(dx, dx, fmaf(dy, dy, dz * dz));
                if (d2 < bestd) { bestd = d2; bestj = j; } // strict <
            }
            // octet combine: smaller d2; tie -> smaller j (first occurrence)
            #pragma unroll
            for (int off = 1; off < LANES_PER_PT; off <<= 1) {
                const float od = __shfl_xor(bestd, off, 64);
                const int   oj = __shfl_xor(bestj, off, 64);
                if (od < bestd || (od == bestd && oj < bestj)) {
                    bestd = od; bestj = oj;
                }
            }
            if (sub == 0) acc = sqrtf(bestd);  // d2 IS |p-t|^2 for the winner
        } else if (sub == 0) {
            const float* tg = targets + ((size_t)b * NPTS + i) * 3;
            const float dx = px - tg[0], dy = py - tg[1], dz = pz - tg[2];
            acc = sqrtf(fmaf(dx, dx, fmaf(dy, dy, dz * dz)));
        }
    }

    // wave-64 reduce
    #pragma unroll
    for (int off = 32; off > 0; off >>= 1)
        acc += __shfl_down(acc, off, 64);

    __shared__ float wsum[THREADS / 64];
    const int wid = tid >> 6, lane = tid & 63;
    if (lane == 0) wsum[wid] = acc;
    __syncthreads();
    if (tid == 0) {
        float s2 = 0.0f;
        #pragma unroll
        for (int w = 0; w < THREADS / 64; ++w) s2 += wsum[w];
        partial[blockIdx.x] = s2;    // plain store, no atomic
    }
}

__global__ __launch_bounds__(256) void pose_loss_reduce(
    const float* __restrict__ partial,   // [NBLK]
    float* __restrict__ out)             // [1]
{
    const int tid = threadIdx.x;
    const float4* p4 = reinterpret_cast<const float4*>(partial);
    float acc = 0.0f;
    #pragma unroll
    for (int k = tid; k < NBLK / 4; k += 256) {
        const float4 v = p4[k];
        acc += (v.x + v.y) + (v.z + v.w);
    }

    #pragma unroll
    for (int off = 32; off > 0; off >>= 1)
        acc += __shfl_down(acc, off, 64);

    __shared__ float wsum[4];
    const int wid = tid >> 6, lane = tid & 63;
    if (lane == 0) wsum[wid] = acc;
    __syncthreads();
    if (tid == 0) {
        float s2 = (wsum[0] + wsum[1]) + (wsum[2] + wsum[3]);
        out[0] = s2 * (1.0f / (BATCH * NPTS));
    }
}

extern "C" void kernel_launch(void* const* d_in, const int* in_sizes, int n_in,
                              void* d_out, int out_size, void* d_ws, size_t ws_size,
                              hipStream_t stream) {
    const float* pred_r       = (const float*)d_in[0];
    const float* pred_t       = (const float*)d_in[1];
    const float* targets      = (const float*)d_in[2];
    const float* model_points = (const float*)d_in[3];
    const int*   idxs         = (const int*)d_in[4];
    float* out     = (float*)d_out;
    float* partial = (float*)d_ws;   // NBLK floats; fully rewritten every call

    pose_loss_kernel<<<NBLK, THREADS, 0, stream>>>(
        pred_r, pred_t, targets, model_points, idxs, partial);
    pose_loss_reduce<<<1, 256, 0, stream>>>(partial, out);
}

// Round 5
// 80.495 us; speedup vs baseline: 1.0025x; 1.0025x over previous
//
#include <hip/hip_runtime.h>
#include <float.h>

// PoseLoss: pred = model @ R^T + t; NN(pred, targets) for symmetric ids
// {0,7,12,20}; loss = mean_b mean_n ||pred - tgt||. B=128, N=1000, fp32.
//
// R5 changes vs R4:
//  - no argmin: d2 = |p-t|^2 computed directly, so loss term = sqrt(min d2).
//    Inner loop is pure min-reduce (drops compare+select index bookkeeping).
//  - packed fp32: targets scanned as float2 pairs (planar LDS float[3][1000],
//    adjacent pair = one ds_read_b64) -> v_pk_{add,fma}_f32, 2 v_min_f32.
//    8 VALU instr / 2 targets vs ~14 scalar.
//  - 4 lanes/point, 125-pair chunks; quad shuffle min combine.
//  - grid 1024 x 512 = exactly 4 blocks/CU (12 KB LDS, 8 waves) one residency.

#define BATCH 128
#define NPTS  1000
#define SPLIT 8
#define PTS_PER_BLK 128                // points per block (4 lanes each)
#define LANES_PER_PT 4
#define NPAIR (NPTS / 2)               // 500
#define PCHUNK (NPAIR / LANES_PER_PT)  // 125 pairs per lane
#define THREADS 512
#define NBLK (BATCH * SPLIT)           // 1024

typedef float f32x2 __attribute__((ext_vector_type(2)));

__global__ __launch_bounds__(THREADS) void pose_loss_kernel(
    const float* __restrict__ pred_r,        // [B,3,3]
    const float* __restrict__ pred_t,        // [B,1,3]
    const float* __restrict__ targets,       // [B,N,3]
    const float* __restrict__ model_points,  // [B,N,3]
    const int*   __restrict__ idxs,          // [B]
    float* __restrict__ partial)             // [NBLK]
{
    const int b   = blockIdx.x / SPLIT;
    const int s   = blockIdx.x % SPLIT;
    const int tid = threadIdx.x;

    const int id = idxs[b];
    const bool sym = (id == 0) | (id == 7) | (id == 12) | (id == 20);

    // batch-uniform R, t -> scalar loads
    const float* Rb = pred_r + b * 9;
    const float* Tb = pred_t + b * 3;
    const float R00 = Rb[0], R01 = Rb[1], R02 = Rb[2];
    const float R10 = Rb[3], R11 = Rb[4], R12 = Rb[5];
    const float R20 = Rb[6], R21 = Rb[7], R22 = Rb[8];
    const float T0 = Tb[0], T1 = Tb[1], T2 = Tb[2];

    // planar layout: tsh[c*1000 + j], c in {x,y,z}
    __shared__ float tsh[3 * NPTS];   // 12 KB
    if (sym) {
        // coalesced float4 reads (targets block is 16B-aligned), planar scatter
        const float4* tb4 =
            reinterpret_cast<const float4*>(targets + (size_t)b * 3 * NPTS);
        for (int k = tid; k < (3 * NPTS) / 4; k += THREADS) {
            const float4 v = tb4[k];
            const int f = 4 * k;
            tsh[((f + 0) % 3) * NPTS + (f + 0) / 3] = v.x;
            tsh[((f + 1) % 3) * NPTS + (f + 1) / 3] = v.y;
            tsh[((f + 2) % 3) * NPTS + (f + 2) / 3] = v.z;
            tsh[((f + 3) % 3) * NPTS + (f + 3) / 3] = v.w;
        }
        __syncthreads();
    }

    const int iloc = tid >> 2;        // 0..127
    const int sub  = tid & 3;         // lane within quad
    const int i    = s * PTS_PER_BLK + iloc;
    const bool valid = (i < NPTS);

    // guarded model load (i can reach 1023 in the last split)
    float m0 = 0.f, m1 = 0.f, m2 = 0.f;
    if (valid) {
        const float* mp = model_points + ((size_t)b * NPTS + i) * 3;
        m0 = mp[0]; m1 = mp[1]; m2 = mp[2];
    }
    const float px = fmaf(m0, R00, fmaf(m1, R01, fmaf(m2, R02, T0)));
    const float py = fmaf(m0, R10, fmaf(m1, R11, fmaf(m2, R12, T1)));
    const float pz = fmaf(m0, R20, fmaf(m1, R21, fmaf(m2, R22, T2)));

    float acc = 0.0f;
    if (sym) {
        const f32x2* tx2 = reinterpret_cast<const f32x2*>(tsh);
        const f32x2* ty2 = reinterpret_cast<const f32x2*>(tsh + NPTS);
        const f32x2* tz2 = reinterpret_cast<const f32x2*>(tsh + 2 * NPTS);
        const f32x2 px2 = {px, px}, py2 = {py, py}, pz2 = {pz, pz};
        f32x2 bd = {FLT_MAX, FLT_MAX};
        const int k0 = sub * PCHUNK;
        // per-instr: 4 distinct b64 addrs (dword 1000c + 250*sub + 2it),
        // bank starts {0,26,20,14} mod 32 -> conflict-free broadcast x16.
        #pragma unroll 5
        for (int k = k0; k < k0 + PCHUNK; ++k) {
            const f32x2 dx = px2 - tx2[k];
            const f32x2 dy = py2 - ty2[k];
            const f32x2 dz = pz2 - tz2[k];
            const f32x2 d2 = dx * dx + dy * dy + dz * dz;  // pk_fma (contract)
            bd.x = fminf(bd.x, d2.x);
            bd.y = fminf(bd.y, d2.y);
        }
        float best = fminf(bd.x, bd.y);
        // quad min combine
        best = fminf(best, __shfl_xor(best, 1, 64));
        best = fminf(best, __shfl_xor(best, 2, 64));
        if (sub == 0 && valid) acc = sqrtf(best);
    } else if (sub == 0 && valid) {
        const float* tg = targets + ((size_t)b * NPTS + i) * 3;
        const float dx = px - tg[0], dy = py - tg[1], dz = pz - tg[2];
        acc = sqrtf(fmaf(dx, dx, fmaf(dy, dy, dz * dz)));
    }

    // wave-64 reduce
    #pragma unroll
    for (int off = 32; off > 0; off >>= 1)
        acc += __shfl_down(acc, off, 64);

    __shared__ float wsum[THREADS / 64];
    const int wid = tid >> 6, lane = tid & 63;
    if (lane == 0) wsum[wid] = acc;
    __syncthreads();
    if (tid == 0) {
        float s2 = 0.0f;
        #pragma unroll
        for (int w = 0; w < THREADS / 64; ++w) s2 += wsum[w];
        partial[blockIdx.x] = s2;    // plain store, no atomic
    }
}

__global__ __launch_bounds__(256) void pose_loss_reduce(
    const float* __restrict__ partial,   // [NBLK]
    float* __restrict__ out)             // [1]
{
    const int tid = threadIdx.x;
    const float4* p4 = reinterpret_cast<const float4*>(partial);
    float acc = 0.0f;
    #pragma unroll
    for (int k = tid; k < NBLK / 4; k += 256) {
        const float4 v = p4[k];
        acc += (v.x + v.y) + (v.z + v.w);
    }

    #pragma unroll
    for (int off = 32; off > 0; off >>= 1)
        acc += __shfl_down(acc, off, 64);

    __shared__ float wsum[4];
    const int wid = tid >> 6, lane = tid & 63;
    if (lane == 0) wsum[wid] = acc;
    __syncthreads();
    if (tid == 0) {
        float s2 = (wsum[0] + wsum[1]) + (wsum[2] + wsum[3]);
        out[0] = s2 * (1.0f / (BATCH * NPTS));
    }
}

extern "C" void kernel_launch(void* const* d_in, const int* in_sizes, int n_in,
                              void* d_out, int out_size, void* d_ws, size_t ws_size,
                              hipStream_t stream) {
    const float* pred_r       = (const float*)d_in[0];
    const float* pred_t       = (const float*)d_in[1];
    const float* targets      = (const float*)d_in[2];
    const float* model_points = (const float*)d_in[3];
    const int*   idxs         = (const int*)d_in[4];
    float* out     = (float*)d_out;
    float* partial = (float*)d_ws;   // NBLK floats; fully rewritten every call

    pose_loss_kernel<<<NBLK, THREADS, 0, stream>>>(
        pred_r, pred_t, targets, model_points, idxs, partial);
    pose_loss_reduce<<<1, 256, 0, stream>>>(partial, out);
}